// Round 9
// baseline (935.786 us; speedup 1.0000x reference)
//
#include <hip/hip_runtime.h>

#define NUSER 50000
#define NITEM 50000
#define NTOT  100000
#define DFEAT 4096
#define DLAT  128
#define DHID  512
#define MTILES 391           // ceil(50000/128) for gemm2
#define MPAD  (MTILES*128)   // 50048
#define G1TILES 782          // ceil(50000/64) for gemm1

typedef __attribute__((ext_vector_type(8))) short bf16x8;
typedef __attribute__((ext_vector_type(4))) float f32x4;

__device__ __forceinline__ ushort f2bf(float f) {
  union { float f; unsigned u; } in; in.f = f;
  unsigned u = in.u;
  u += 0x7fffu + ((u >> 16) & 1u);   // round-to-nearest-even
  return (ushort)(u >> 16);
}
// half-up rounding pack of two fp32 -> 2xbf16
__device__ __forceinline__ unsigned pk2bf_fast(float lo, float hi) {
  unsigned ul = __float_as_uint(lo) + 0x8000u;
  unsigned uh = __float_as_uint(hi) + 0x8000u;
  return (ul >> 16) | (uh & 0xffff0000u);
}
__device__ __forceinline__ float bflo(unsigned u) { return __uint_as_float(u << 16); }
__device__ __forceinline__ float bfhi(unsigned u) { return __uint_as_float(u & 0xffff0000u); }

// ================= GEMM1: Hid = leakyrelu(A(fp32) @ W1 + b1) =================
// R5 geometry (BM=64, BN=512, BK=64, 8 waves, wave tile 64x64) + T3/T4
// counted-vmcnt double-buffered pipeline (2x(8+64)KB = 144KB LDS, 1 blk/CU):
//   barrier#1 -> issue A(t+1)[2 ld] + B(t+1)[8 gload_lds] -> vmcnt(10)
//   -> ds_write A(t) -> lgkmcnt(0) -> barrier#2 -> MFMA(t).
// Tile t+1's 10 VMEM ops stay IN FLIGHT across both barriers and the MFMA
// phase — never vmcnt(0) in the main loop (final step only). Per-wave VMEM
// count is exec-safe: A rows clamped (min(row,NITEM-1)) so EVERY wave issues
// exactly 10 ops/step. XOR-swizzled 16B slots (slot ^= row&7) conflict-free.
__global__ __launch_bounds__(512, 2) void gemm1_kernel(
    const float* __restrict__ A,    // [NITEM][DFEAT] fp32
    const ushort* __restrict__ BT,  // [DHID][DFEAT] bf16 (W1 transposed)
    const float* __restrict__ bias, // [DHID]
    ushort* __restrict__ Hid)       // [MPAD][DHID] bf16
{
  extern __shared__ char smem[];
  char* const As0 = smem;                    // 8192 B
  char* const As1 = smem + 8192;             // 8192 B
  char* const Bs0 = smem + 16384;            // 65536 B
  char* const Bs1 = smem + 16384 + 65536;    // 65536 B

  const int tid = threadIdx.x;
  const int lane = tid & 63;
  const int wid = tid >> 6;          // 0..7 = column block
  const int row0 = blockIdx.x * 64;

  const int lr = lane & 15;
  const int kq = lane >> 4;          // 0..3
  const int l7 = lane & 7;

  f32x4 acc[4][4];
  const f32x4 z = {0.f, 0.f, 0.f, 0.f};
  #pragma unroll
  for (int m = 0; m < 4; ++m)
    #pragma unroll
    for (int n = 0; n < 4; ++n) acc[m][n] = z;

  // A staging: 512 16B-slots, 1/thread: row r0 (0..63), k-octet t0 (0..7).
  // Row clamped so the load is UNCONDITIONAL (uniform vmcnt count per wave).
  // Pad rows get duplicate data; their outputs are garbage-but-isolated
  // (MFMA row i depends only on A row i) and never stored past NITEM rows
  // downstream.
  const int r0 = tid >> 3, t0 = tid & 7;
  const int aoff = r0 * 128 + ((t0 ^ (r0 & 7)) << 4);
  const int arow = min(row0 + r0, NITEM - 1);
  const float* aptr = A + (size_t)arow * DFEAT + t0 * 8;

  auto issueB = [&](char* dstB, int k0) {
    #pragma unroll
    for (int j = 0; j < 8; ++j) {
      int q = (wid * 8 + j) * 64 + lane;     // 0..4095
      int r = q >> 3, t = q & 7;
      const ushort* src = BT + (size_t)r * DFEAT + k0 + ((t ^ (r & 7)) << 3);
      __builtin_amdgcn_global_load_lds(
          (const __attribute__((address_space(1))) void*)src,
          (__attribute__((address_space(3))) void*)(dstB + (size_t)(wid * 8 + j) * 1024),
          16, 0, 0);
    }
  };
  auto compute = [&](const char* AsC, const char* BsC) {
    #pragma unroll
    for (int kk = 0; kk < 2; ++kk) {
      const int c8 = kk * 4 + kq;
      const int sx = (c8 ^ l7) << 4;
      bf16x8 a[4], b[4];
      #pragma unroll
      for (int m = 0; m < 4; ++m)
        a[m] = *(const bf16x8*)(AsC + (m * 16 + lr) * 128 + sx);
      #pragma unroll
      for (int n = 0; n < 4; ++n)
        b[n] = *(const bf16x8*)(BsC + (wid * 64 + n * 16 + lr) * 128 + sx);
      #pragma unroll
      for (int m = 0; m < 4; ++m)
        #pragma unroll
        for (int n = 0; n < 4; ++n)
          acc[m][n] = __builtin_amdgcn_mfma_f32_16x16x32_bf16(a[m], b[n], acc[m][n], 0, 0, 0);
    }
  };

  // A(t) regs held across one iteration
  float4 c0, c1;

  // one pipelined K-step (tile t computed from (Asc,Bsc); t+1 staged to (Asn,Bsn))
  auto iterstep = [&](int t, char* Asc, char* Bsc, char* Asn, char* Bsn) {
    __builtin_amdgcn_s_barrier();                 // #1: compute(t-1) done everywhere
    __builtin_amdgcn_sched_barrier(0);
    float4 n0 = {0.f, 0.f, 0.f, 0.f}, n1 = n0;
    if (t < 63) {
      const float* s = aptr + (size_t)(t + 1) * 64;
      n0 = *(const float4*)s;                     // A(t+1): 2 VMEM
      n1 = *(const float4*)(s + 4);
      issueB(Bsn, (t + 1) * 64);                  // B(t+1): 8 VMEM -> other buf
      asm volatile("s_waitcnt vmcnt(10)" ::: "memory");  // tile-t's 10 done; t+1 in flight
    } else {
      asm volatile("s_waitcnt vmcnt(0)" ::: "memory");   // last tile: drain
    }
    __builtin_amdgcn_sched_barrier(0);
    uint4 p;
    p.x = pk2bf_fast(c0.x, c0.y); p.y = pk2bf_fast(c0.z, c0.w);
    p.z = pk2bf_fast(c1.x, c1.y); p.w = pk2bf_fast(c1.z, c1.w);
    *(uint4*)(Asc + aoff) = p;                    // A(t) -> LDS
    asm volatile("s_waitcnt lgkmcnt(0)" ::: "memory");
    __builtin_amdgcn_s_barrier();                 // #2: tile t fully in LDS
    __builtin_amdgcn_sched_barrier(0);
    compute(Asc, Bsc);
    __builtin_amdgcn_sched_barrier(0);
    c0 = n0; c1 = n1;
  };

  // ---- prologue: issue tile 0 (A regs + B DMA into buf0) ----
  c0 = *(const float4*)aptr;
  c1 = *(const float4*)(aptr + 4);
  issueB(Bs0, 0);

  // ---- main loop: 64 steps, buffers alternate at compile time ----
  for (int t = 0; t < 64; t += 2) {
    iterstep(t,     As0, Bs0, As1, Bs1);
    iterstep(t + 1, As1, Bs1, As0, Bs0);
  }

  // ---- epilogue: +bias, leakyrelu, bf16 store (pad rows finite-or-NaN, isolated) ----
  #pragma unroll
  for (int n = 0; n < 4; ++n) {
    int col = wid * 64 + n * 16 + lr;
    float bv = bias[col];
    #pragma unroll
    for (int m = 0; m < 4; ++m) {
      #pragma unroll
      for (int i = 0; i < 4; ++i) {
        int row = row0 + m * 16 + kq * 4 + i;
        float v = acc[m][n][i] + bv;
        v = v > 0.f ? v : 0.01f * v;
        Hid[(size_t)row * DHID + col] = f2bf(v);
      }
    }
  }
}

#define BM 128
#define BK 32
#define LDW 40   // padded LDS row stride (ushorts)

// ---------------- GEMM2: item_feat = hidden @ W2 + b2 -> X rows [NUSER..NTOT) fp32 ----------------
__global__ __launch_bounds__(256, 4) void gemm2_kernel(
    const ushort* __restrict__ A,   // Hid [MPAD][DHID] bf16
    const ushort* __restrict__ BT,  // W2T [DLAT][DHID] bf16
    const float* __restrict__ bias, // [DLAT]
    float* __restrict__ X)          // [NTOT][DLAT]
{
  __shared__ ushort As[BM][LDW];
  __shared__ ushort Bs[BM][LDW];
  const int tid = threadIdx.x;
  const int lane = tid & 63;
  const int wid = tid >> 6;
  const int wr = wid >> 1, wc = wid & 1;
  const int row0 = blockIdx.x * BM;

  f32x4 acc[4][4];
  const f32x4 z = {0.f, 0.f, 0.f, 0.f};
  #pragma unroll
  for (int m = 0; m < 4; ++m)
    #pragma unroll
    for (int n = 0; n < 4; ++n) acc[m][n] = z;

  const int lrow = lane & 15;
  const int kb = (lane >> 4) * 8;

  for (int k0 = 0; k0 < DHID; k0 += BK) {
    #pragma unroll
    for (int j = 0; j < 2; ++j) {
      int idx = tid + j * 256;
      int r = idx >> 2;
      int c8 = (idx & 3) << 3;
      *(uint4*)&As[r][c8] = *(const uint4*)(A + (size_t)(row0 + r) * DHID + k0 + c8);
      *(uint4*)&Bs[r][c8] = *(const uint4*)(BT + (size_t)r * DHID + k0 + c8);
    }
    __syncthreads();
    bf16x8 a[4], b[4];
    #pragma unroll
    for (int m = 0; m < 4; ++m) a[m] = *(const bf16x8*)&As[wr * 64 + m * 16 + lrow][kb];
    #pragma unroll
    for (int n = 0; n < 4; ++n) b[n] = *(const bf16x8*)&Bs[wc * 64 + n * 16 + lrow][kb];
    #pragma unroll
    for (int m = 0; m < 4; ++m)
      #pragma unroll
      for (int n = 0; n < 4; ++n)
        acc[m][n] = __builtin_amdgcn_mfma_f32_16x16x32_bf16(a[m], b[n], acc[m][n], 0, 0, 0);
    __syncthreads();
  }
  #pragma unroll
  for (int n = 0; n < 4; ++n) {
    int col = wc * 64 + n * 16 + lrow;
    float bv = bias[col];
    #pragma unroll
    for (int m = 0; m < 4; ++m) {
      #pragma unroll
      for (int i = 0; i < 4; ++i) {
        int row = row0 + wr * 64 + m * 16 + (lane >> 4) * 4 + i;
        if (row < NITEM)
          X[(size_t)(NUSER + row) * DLAT + col] = acc[m][n][i] + bv;
      }
    }
  }
}

// ---------------- prep: coalesced LDS-tile transpose + fp32->bf16 ----------------
__global__ __launch_bounds__(256) void prep_w1t(const float* __restrict__ W1,
                                                ushort* __restrict__ W1T) {
  __shared__ ushort t[64][72];
  const int bx = blockIdx.x & 63;
  const int by = blockIdx.x >> 6;
  const int k0 = bx * 64, n0 = by * 64;
  const int tid = threadIdx.x;
  #pragma unroll
  for (int j = 0; j < 4; ++j) {
    int f = tid + j * 256;
    int r = f >> 4, c4 = (f & 15) << 2;
    float4 v = *(const float4*)(W1 + (size_t)(k0 + r) * DHID + n0 + c4);
    t[c4 + 0][r] = f2bf(v.x);
    t[c4 + 1][r] = f2bf(v.y);
    t[c4 + 2][r] = f2bf(v.z);
    t[c4 + 3][r] = f2bf(v.w);
  }
  __syncthreads();
  #pragma unroll
  for (int j = 0; j < 2; ++j) {
    int o = tid + j * 256;
    int r = o >> 3, c8 = (o & 7) << 3;
    *(uint4*)(W1T + (size_t)(n0 + r) * DFEAT + k0 + c8) = *(const uint4*)&t[r][c8];
  }
}
__global__ void prep_w2t(const float* __restrict__ W2, ushort* __restrict__ W2T) {
  int idx = blockIdx.x * 256 + threadIdx.x;
  int n = idx >> 9, k = idx & 511;
  W2T[idx] = f2bf(W2[(size_t)k * DLAT + n]);
}

// ------- normalize rows of x; also emit bf16 copy Xb for spmm gathers -------
__global__ __launch_bounds__(256) void normalize_kernel(
    const float* __restrict__ pref, float* __restrict__ X,
    unsigned* __restrict__ Xb) {
  int gw = (blockIdx.x * 256 + threadIdx.x) >> 6;
  int lane = threadIdx.x & 63;
  if (gw >= NTOT) return;
  const float* src = (gw < NUSER) ? (pref + (size_t)gw * DLAT) : (X + (size_t)gw * DLAT);
  float2 v = *(const float2*)(src + lane * 2);
  float s = v.x * v.x + v.y * v.y;
  #pragma unroll
  for (int off = 32; off; off >>= 1) s += __shfl_xor(s, off, 64);
  float inv = 1.0f / fmaxf(sqrtf(s), 1e-12f);
  float2 o; o.x = v.x * inv; o.y = v.y * inv;
  *(float2*)(X + (size_t)gw * DLAT + lane * 2) = o;
  Xb[(size_t)gw * 64 + lane] = pk2bf_fast(o.x, o.y);
}

// ---------------- graph prep: CSR by destination ----------------
__global__ void count_kernel(const int* __restrict__ col, int* __restrict__ cnt, int E) {
  int e = blockIdx.x * 256 + threadIdx.x;
  if (e < E) atomicAdd(&cnt[col[e]], 1);
}
__global__ void dinv_kernel(const int* __restrict__ cnt, float* __restrict__ dinv, int n) {
  int i = blockIdx.x * 256 + threadIdx.x;
  if (i < n) dinv[i] = rsqrtf((float)cnt[i]);
}

// ---------------- two-level scan ----------------
#define SCAN_NB ((NTOT + 1023) / 1024)   // 98
__global__ __launch_bounds__(1024) void scan1_kernel(const int* __restrict__ cnt,
                                                     int* __restrict__ off,
                                                     int* __restrict__ bsum, int n) {
  __shared__ int ws[16];
  __shared__ int wexcl[16];
  const int tid = threadIdx.x, lane = tid & 63, wv = tid >> 6;
  int i = blockIdx.x * 1024 + tid;
  int v = (i < n) ? cnt[i] : 0;
  int x = v;
  #pragma unroll
  for (int o = 1; o < 64; o <<= 1) {
    int t = __shfl_up(x, o, 64);
    if (lane >= o) x += t;
  }
  if (lane == 63) ws[wv] = x;
  __syncthreads();
  if (tid < 16) {
    int y = ws[tid];
    #pragma unroll
    for (int o = 1; o < 16; o <<= 1) {
      int t = __shfl_up(y, o, 64);
      if (tid >= o) y += t;
    }
    wexcl[tid] = y - ws[tid];
    if (tid == 15) bsum[blockIdx.x] = y;
  }
  __syncthreads();
  if (i < n) off[i] = wexcl[wv] + (x - v);
}
__global__ __launch_bounds__(128) void scan2_kernel(int* __restrict__ bsum,
                                                    int* __restrict__ off, int nb, int n) {
  __shared__ int ws[2];
  const int tid = threadIdx.x, lane = tid & 63, wv = tid >> 6;
  int v = (tid < nb) ? bsum[tid] : 0;
  int x = v;
  #pragma unroll
  for (int o = 1; o < 64; o <<= 1) {
    int t = __shfl_up(x, o, 64);
    if (lane >= o) x += t;
  }
  if (lane == 63) ws[wv] = x;
  __syncthreads();
  int excl_w = (wv == 1) ? ws[0] : 0;
  if (tid < nb) bsum[tid] = excl_w + (x - v);
  if (tid == nb - 1) off[n] = excl_w + x;
}
__global__ __launch_bounds__(1024) void scan3_kernel(int* __restrict__ off,
                                                     const int* __restrict__ bsum, int n) {
  int i = blockIdx.x * 1024 + threadIdx.x;
  if (i < n) off[i] += bsum[blockIdx.x];
}

// fill CSR slots: (src, edge-norm) packed per dst segment
__global__ void fill_kernel(const int* __restrict__ row, const int* __restrict__ col,
                            const float* __restrict__ dinv, const int* __restrict__ off,
                            int* __restrict__ cur, int2* __restrict__ srcw, int E) {
  int e = blockIdx.x * 256 + threadIdx.x;
  if (e >= E) return;
  int r = row[e], c = col[e];
  float w = dinv[r] * dinv[c];
  int p = atomicAdd(&cur[c], 1);
  int2 pk; pk.x = r; pk.y = __float_as_int(w);
  srcw[off[c] + p] = pk;
}

// -------- SpMM: one wave per node, bf16 gathers, fp32 accumulate --------
// FINAL=0: hout fp32 + houtb bf16 copy.  FINAL=1: hout = gather + addA + addB.
template <int FINAL>
__global__ __launch_bounds__(256) void spmm_kernel(
    const int2* __restrict__ srcw, const int* __restrict__ off,
    const unsigned* __restrict__ hb, float* __restrict__ hout,
    unsigned* __restrict__ houtb,
    const float* __restrict__ addA, const float* __restrict__ addB) {
  int node = (int)((blockIdx.x * 256 + threadIdx.x) >> 6);
  int lane = threadIdx.x & 63;
  if (node >= NTOT) return;
  int p = off[node], pend = off[node + 1];
  float ax = 0.f, ay = 0.f;
  for (; p + 3 < pend; p += 4) {
    int2 e0 = srcw[p];
    int2 e1 = srcw[p + 1];
    int2 e2 = srcw[p + 2];
    int2 e3 = srcw[p + 3];
    unsigned u0 = hb[(size_t)e0.x * 64 + lane];
    unsigned u1 = hb[(size_t)e1.x * 64 + lane];
    unsigned u2 = hb[(size_t)e2.x * 64 + lane];
    unsigned u3 = hb[(size_t)e3.x * 64 + lane];
    float w0 = __int_as_float(e0.y), w1 = __int_as_float(e1.y);
    float w2 = __int_as_float(e2.y), w3 = __int_as_float(e3.y);
    ax += w0 * bflo(u0) + w1 * bflo(u1) + w2 * bflo(u2) + w3 * bflo(u3);
    ay += w0 * bfhi(u0) + w1 * bfhi(u1) + w2 * bfhi(u2) + w3 * bfhi(u3);
  }
  for (; p < pend; ++p) {
    int2 e0 = srcw[p];
    float w0 = __int_as_float(e0.y);
    unsigned u0 = hb[(size_t)e0.x * 64 + lane];
    ax += w0 * bflo(u0);
    ay += w0 * bfhi(u0);
  }
  size_t o = (size_t)node * DLAT + lane * 2;
  if (FINAL) {
    float2 a = *(const float2*)(addA + o);
    float2 b = *(const float2*)(addB + o);
    ax += a.x + b.x;
    ay += a.y + b.y;
  } else {
    houtb[(size_t)node * 64 + lane] = pk2bf_fast(ax, ay);
  }
  float2 r; r.x = ax; r.y = ay;
  *(float2*)(hout + o) = r;
}

extern "C" void kernel_launch(void* const* d_in, const int* in_sizes, int n_in,
                              void* d_out, int out_size, void* d_ws, size_t ws_size,
                              hipStream_t stream) {
  const float* features  = (const float*)d_in[0];
  const float* preference = (const float*)d_in[1];
  const float* W1 = (const float*)d_in[2];
  const float* b1 = (const float*)d_in[3];
  const float* W2 = (const float*)d_in[4];
  const float* b2 = (const float*)d_in[5];
  const int*   edges = (const int*)d_in[6];
  const int E = in_sizes[6] / 2;
  const int* erow = edges;
  const int* ecol = edges + E;
  float* out = (float*)d_out;

  char* ws = (char*)d_ws;
  size_t off_b = 0;
  auto alloc = [&](size_t bytes) {
    void* p = ws + off_b;
    off_b = (off_b + bytes + 255) & ~(size_t)255;
    return p;
  };
  ushort*   W1T  = (ushort*)alloc((size_t)DHID * DFEAT * 2);   // 4.2 MB
  ushort*   W2T  = (ushort*)alloc((size_t)DLAT * DHID * 2);    // 0.13 MB
  ushort*   Hid  = (ushort*)alloc((size_t)MPAD * DHID * 2);    // 51.2 MB
  float*    X    = (float*)alloc((size_t)NTOT * DLAT * 4);     // 51.2 MB
  float*    hA   = (float*)alloc((size_t)NTOT * DLAT * 4);     // 51.2 MB
  unsigned* Xb   = (unsigned*)alloc((size_t)NTOT * 64 * 4);    // 25.6 MB
  unsigned* hAb  = (unsigned*)alloc((size_t)NTOT * 64 * 4);    // 25.6 MB
  int*      cnt  = (int*)alloc((size_t)NTOT * 4);
  int*      offs = (int*)alloc((size_t)(NTOT + 1) * 4);
  int*      cur  = (int*)alloc((size_t)NTOT * 4);
  float*    dinv = (float*)alloc((size_t)NTOT * 4);
  int*      bsum = (int*)alloc((size_t)SCAN_NB * 4);
  int2*     srcw = (int2*)alloc((size_t)E * 8);                // 12.8 MB

  // projection MLP + normalize
  prep_w1t<<<512, 256, 0, stream>>>(W1, W1T);
  prep_w2t<<<(DLAT * DHID) / 256, 256, 0, stream>>>(W2, W2T);
  gemm1_kernel<<<G1TILES, 512, 144 * 1024, stream>>>(features, W1T, b1, Hid);
  gemm2_kernel<<<MTILES, 256, 0, stream>>>(Hid, W2T, b2, X);
  normalize_kernel<<<(NTOT * 64 + 255) / 256, 256, 0, stream>>>(preference, X, Xb);

  // CSR build (by destination); symmetric edge list => cnt doubles as deg
  hipMemsetAsync(cnt, 0, (size_t)NTOT * 4, stream);
  count_kernel<<<(E + 255) / 256, 256, 0, stream>>>(ecol, cnt, E);
  dinv_kernel<<<(NTOT + 255) / 256, 256, 0, stream>>>(cnt, dinv, NTOT);
  scan1_kernel<<<SCAN_NB, 1024, 0, stream>>>(cnt, offs, bsum, NTOT);
  scan2_kernel<<<1, 128, 0, stream>>>(bsum, offs, SCAN_NB, NTOT);
  scan3_kernel<<<SCAN_NB, 1024, 0, stream>>>(offs, bsum, NTOT);
  hipMemsetAsync(cur, 0, (size_t)NTOT * 4, stream);
  fill_kernel<<<(E + 255) / 256, 256, 0, stream>>>(erow, ecol, dinv, offs, cur, srcw, E);

  // two propagation layers; layer 2 fuses out = X + h1 + h2
  spmm_kernel<0><<<(NTOT * 64 + 255) / 256, 256, 0, stream>>>(srcw, offs, Xb, hA, hAb, nullptr, nullptr);
  spmm_kernel<1><<<(NTOT * 64 + 255) / 256, 256, 0, stream>>>(srcw, offs, hAb, out, nullptr, X, hA);

  // output 1: preference passthrough
  hipMemcpyAsync(out + (size_t)NTOT * DLAT, preference, (size_t)NUSER * DLAT * 4,
                 hipMemcpyDeviceToDevice, stream);
}

// Round 10
// 738.946 us; speedup vs baseline: 1.2664x; 1.2664x over previous
//
#include <hip/hip_runtime.h>

#define NUSER 50000
#define NITEM 50000
#define NTOT  100000
#define DFEAT 4096
#define DLAT  128
#define DHID  512
#define MTILES 391           // ceil(50000/128) for gemm2
#define MPAD  (MTILES*128)   // 50048
#define G1TILES 782          // ceil(50000/64) for gemm1

typedef __attribute__((ext_vector_type(8))) short bf16x8;
typedef __attribute__((ext_vector_type(4))) float f32x4;

__device__ __forceinline__ ushort f2bf(float f) {
  union { float f; unsigned u; } in; in.f = f;
  unsigned u = in.u;
  u += 0x7fffu + ((u >> 16) & 1u);   // round-to-nearest-even
  return (ushort)(u >> 16);
}
// half-up rounding pack of two fp32 -> 2xbf16
__device__ __forceinline__ unsigned pk2bf_fast(float lo, float hi) {
  unsigned ul = __float_as_uint(lo) + 0x8000u;
  unsigned uh = __float_as_uint(hi) + 0x8000u;
  return (ul >> 16) | (uh & 0xffff0000u);
}
__device__ __forceinline__ float bflo(unsigned u) { return __uint_as_float(u << 16); }
__device__ __forceinline__ float bfhi(unsigned u) { return __uint_as_float(u & 0xffff0000u); }

// ================= GEMM1 (R8 exact — proven fastest at ~410us) =================
// BM=64, BN=512 (A read once), BK=64, 8 waves, wave tile 64x64, 72KB LDS,
// 2 barriers/step, __launch_bounds__(512,4). XOR-swizzled 16B slots
// (slot ^= row&7): conflict-free ds_write/ds_read; B via global_load_lds
// (pre-swizzled global source, linear LDS dest).
__global__ __launch_bounds__(512, 4) void gemm1_kernel(
    const float* __restrict__ A,    // [NITEM][DFEAT] fp32
    const ushort* __restrict__ BT,  // [DHID][DFEAT] bf16 (W1 transposed)
    const float* __restrict__ bias, // [DHID]
    ushort* __restrict__ Hid)       // [MPAD][DHID] bf16
{
  extern __shared__ char smem[];
  char* AsC = smem;             // 64*64*2   = 8192 B
  char* BsC = smem + 8192;      // 512*64*2  = 65536 B

  const int tid = threadIdx.x;
  const int lane = tid & 63;
  const int wid = tid >> 6;          // 0..7 = column block
  const int row0 = blockIdx.x * 64;

  const int lr = lane & 15;
  const int kq = lane >> 4;          // 0..3
  const int l7 = lane & 7;

  f32x4 acc[4][4];
  const f32x4 z = {0.f, 0.f, 0.f, 0.f};
  #pragma unroll
  for (int m = 0; m < 4; ++m)
    #pragma unroll
    for (int n = 0; n < 4; ++n) acc[m][n] = z;

  const int r0 = tid >> 3, t0 = tid & 7;
  const int aoff = r0 * 128 + ((t0 ^ (r0 & 7)) << 4);
  const size_t asrc = (size_t)(row0 + r0) * DFEAT + t0 * 8;
  const bool aok = (row0 + r0) < NITEM;

  for (int k0 = 0; k0 < DFEAT; k0 += 64) {
    #pragma unroll
    for (int j = 0; j < 8; ++j) {
      int q = (wid * 8 + j) * 64 + lane;     // 0..4095
      int r = q >> 3, t = q & 7;
      const ushort* src = BT + (size_t)r * DFEAT + k0 + ((t ^ (r & 7)) << 3);
      __builtin_amdgcn_global_load_lds(
          (const __attribute__((address_space(1))) void*)src,
          (__attribute__((address_space(3))) void*)(BsC + (size_t)(wid * 8 + j) * 1024),
          16, 0, 0);
    }
    {
      float4 v0 = make_float4(0.f, 0.f, 0.f, 0.f), v1 = v0;
      if (aok) {
        const float* s = A + asrc + k0;
        v0 = *(const float4*)s; v1 = *(const float4*)(s + 4);
      }
      uint4 p;
      p.x = pk2bf_fast(v0.x, v0.y); p.y = pk2bf_fast(v0.z, v0.w);
      p.z = pk2bf_fast(v1.x, v1.y); p.w = pk2bf_fast(v1.z, v1.w);
      *(uint4*)(AsC + aoff) = p;
    }
    __syncthreads();   // drains gload_lds (vmcnt) + ds_writes (lgkm)

    #pragma unroll
    for (int kk = 0; kk < 2; ++kk) {
      const int c8 = kk * 4 + kq;
      const int sx = (c8 ^ l7) << 4;
      bf16x8 a[4], b[4];
      #pragma unroll
      for (int m = 0; m < 4; ++m)
        a[m] = *(const bf16x8*)(AsC + (m * 16 + lr) * 128 + sx);
      #pragma unroll
      for (int n = 0; n < 4; ++n)
        b[n] = *(const bf16x8*)(BsC + (wid * 64 + n * 16 + lr) * 128 + sx);
      #pragma unroll
      for (int m = 0; m < 4; ++m)
        #pragma unroll
        for (int n = 0; n < 4; ++n)
          acc[m][n] = __builtin_amdgcn_mfma_f32_16x16x32_bf16(a[m], b[n], acc[m][n], 0, 0, 0);
    }
    __syncthreads();
  }

  #pragma unroll
  for (int n = 0; n < 4; ++n) {
    int col = wid * 64 + n * 16 + lr;
    float bv = bias[col];
    #pragma unroll
    for (int m = 0; m < 4; ++m) {
      #pragma unroll
      for (int i = 0; i < 4; ++i) {
        int row = row0 + m * 16 + kq * 4 + i;
        float v = acc[m][n][i] + bv;
        v = v > 0.f ? v : 0.01f * v;
        Hid[(size_t)row * DHID + col] = f2bf(v);
      }
    }
  }
}

#define BM 128
#define BK 32
#define LDW 40   // padded LDS row stride (ushorts)

// ======= GEMM2 + fused L2-normalize: X = normalize(Hid @ W2 + b2) =======
// Block = 128 rows x 128 cols (full DLAT) -> block owns COMPLETE rows, so
// the row L2-norm fuses here: per-wave partial sum-of-squares -> 4x shfl_xor
// over the 16-lane lr group -> 2-phase LDS add across the wc=0/1 waves.
// Emits normalized X (fp32) AND Xb (bf16 pairs) for the spmm gathers.
__global__ __launch_bounds__(256, 4) void gemm2_kernel(
    const ushort* __restrict__ A,   // Hid [MPAD][DHID] bf16
    const ushort* __restrict__ BT,  // W2T [DLAT][DHID] bf16
    const float* __restrict__ bias, // [DLAT]
    float* __restrict__ X,          // [NTOT][DLAT] (items at NUSER+)
    unsigned* __restrict__ Xb)      // [NTOT][64] bf16-pairs
{
  __shared__ ushort As[BM][LDW];
  __shared__ ushort Bs[BM][LDW];
  __shared__ float rsum[BM];
  const int tid = threadIdx.x;
  const int lane = tid & 63;
  const int wid = tid >> 6;
  const int wr = wid >> 1, wc = wid & 1;
  const int row0 = blockIdx.x * BM;

  f32x4 acc[4][4];
  const f32x4 z = {0.f, 0.f, 0.f, 0.f};
  #pragma unroll
  for (int m = 0; m < 4; ++m)
    #pragma unroll
    for (int n = 0; n < 4; ++n) acc[m][n] = z;

  const int lrow = lane & 15;
  const int kq = lane >> 4;
  const int kb = kq * 8;

  for (int k0 = 0; k0 < DHID; k0 += BK) {
    #pragma unroll
    for (int j = 0; j < 2; ++j) {
      int idx = tid + j * 256;
      int r = idx >> 2;
      int c8 = (idx & 3) << 3;
      *(uint4*)&As[r][c8] = *(const uint4*)(A + (size_t)(row0 + r) * DHID + k0 + c8);
      *(uint4*)&Bs[r][c8] = *(const uint4*)(BT + (size_t)r * DHID + k0 + c8);
    }
    __syncthreads();
    bf16x8 a[4], b[4];
    #pragma unroll
    for (int m = 0; m < 4; ++m) a[m] = *(const bf16x8*)&As[wr * 64 + m * 16 + lrow][kb];
    #pragma unroll
    for (int n = 0; n < 4; ++n) b[n] = *(const bf16x8*)&Bs[wc * 64 + n * 16 + lrow][kb];
    #pragma unroll
    for (int m = 0; m < 4; ++m)
      #pragma unroll
      for (int n = 0; n < 4; ++n)
        acc[m][n] = __builtin_amdgcn_mfma_f32_16x16x32_bf16(a[m], b[n], acc[m][n], 0, 0, 0);
    __syncthreads();
  }

  // ---- fused epilogue: row norms ----
  float prt[4][4];   // [m][i] partial sum of squares over this wave's 64 cols
  #pragma unroll
  for (int m = 0; m < 4; ++m)
    #pragma unroll
    for (int i = 0; i < 4; ++i) prt[m][i] = 0.f;
  #pragma unroll
  for (int n = 0; n < 4; ++n) {
    float bv = bias[wc * 64 + n * 16 + lrow];
    #pragma unroll
    for (int m = 0; m < 4; ++m)
      #pragma unroll
      for (int i = 0; i < 4; ++i) {
        float v = acc[m][n][i] + bv;
        prt[m][i] += v * v;
      }
  }
  // reduce over the 16-lane lr group (lane = kq*16 + lr; masks stay in-group)
  #pragma unroll
  for (int msk = 1; msk < 16; msk <<= 1)
    #pragma unroll
    for (int m = 0; m < 4; ++m)
      #pragma unroll
      for (int i = 0; i < 4; ++i)
        prt[m][i] += __shfl_xor(prt[m][i], msk, 64);
  // cross-wave (wc=0 then wc=1) via LDS, one writer (lr==0) per row
  if (wc == 0 && lrow == 0) {
    #pragma unroll
    for (int m = 0; m < 4; ++m)
      #pragma unroll
      for (int i = 0; i < 4; ++i)
        rsum[wr * 64 + m * 16 + kq * 4 + i] = prt[m][i];
  }
  __syncthreads();
  if (wc == 1 && lrow == 0) {
    #pragma unroll
    for (int m = 0; m < 4; ++m)
      #pragma unroll
      for (int i = 0; i < 4; ++i)
        rsum[wr * 64 + m * 16 + kq * 4 + i] += prt[m][i];
  }
  __syncthreads();

  // ---- normalized store: X fp32 + Xb bf16 pairs ----
  #pragma unroll
  for (int n = 0; n < 4; ++n) {
    int col = wc * 64 + n * 16 + lrow;
    float bv = bias[col];
    #pragma unroll
    for (int m = 0; m < 4; ++m) {
      #pragma unroll
      for (int i = 0; i < 4; ++i) {
        int rl = wr * 64 + m * 16 + kq * 4 + i;
        int row = row0 + rl;
        float inv = rsqrtf(fmaxf(rsum[rl], 1e-24f));
        float v = (acc[m][n][i] + bv) * inv;
        float vo = __shfl_xor(v, 1, 64);   // neighbor col (lr^1)
        if (row < NITEM) {
          size_t node = (size_t)(NUSER + row);
          X[node * DLAT + col] = v;
          if ((lrow & 1) == 0)
            Xb[node * 64 + (col >> 1)] = pk2bf_fast(v, vo);
        }
      }
    }
  }
}

// ---------------- prep: coalesced LDS-tile transpose + fp32->bf16 ----------------
__global__ __launch_bounds__(256) void prep_w1t(const float* __restrict__ W1,
                                                ushort* __restrict__ W1T) {
  __shared__ ushort t[64][72];
  const int bx = blockIdx.x & 63;
  const int by = blockIdx.x >> 6;
  const int k0 = bx * 64, n0 = by * 64;
  const int tid = threadIdx.x;
  #pragma unroll
  for (int j = 0; j < 4; ++j) {
    int f = tid + j * 256;
    int r = f >> 4, c4 = (f & 15) << 2;
    float4 v = *(const float4*)(W1 + (size_t)(k0 + r) * DHID + n0 + c4);
    t[c4 + 0][r] = f2bf(v.x);
    t[c4 + 1][r] = f2bf(v.y);
    t[c4 + 2][r] = f2bf(v.z);
    t[c4 + 3][r] = f2bf(v.w);
  }
  __syncthreads();
  #pragma unroll
  for (int j = 0; j < 2; ++j) {
    int o = tid + j * 256;
    int r = o >> 3, c8 = (o & 7) << 3;
    *(uint4*)(W1T + (size_t)(n0 + r) * DFEAT + k0 + c8) = *(const uint4*)&t[r][c8];
  }
}
__global__ void prep_w2t(const float* __restrict__ W2, ushort* __restrict__ W2T) {
  int idx = blockIdx.x * 256 + threadIdx.x;
  int n = idx >> 9, k = idx & 511;
  W2T[idx] = f2bf(W2[(size_t)k * DLAT + n]);
}

// ------- normalize user rows (preference) -> X fp32 + Xb bf16 -------
__global__ __launch_bounds__(256) void normalize_pref(
    const float* __restrict__ pref, float* __restrict__ X,
    unsigned* __restrict__ Xb) {
  int gw = (blockIdx.x * 256 + threadIdx.x) >> 6;
  int lane = threadIdx.x & 63;
  if (gw >= NUSER) return;
  float2 v = *(const float2*)(pref + (size_t)gw * DLAT + lane * 2);
  float s = v.x * v.x + v.y * v.y;
  #pragma unroll
  for (int off = 32; off; off >>= 1) s += __shfl_xor(s, off, 64);
  float inv = 1.0f / fmaxf(sqrtf(s), 1e-12f);
  float2 o; o.x = v.x * inv; o.y = v.y * inv;
  *(float2*)(X + (size_t)gw * DLAT + lane * 2) = o;
  Xb[(size_t)gw * 64 + lane] = pk2bf_fast(o.x, o.y);
}

// ---------------- graph prep: CSR by destination ----------------
__global__ void count_kernel(const int* __restrict__ col, int* __restrict__ cnt, int E) {
  int e = blockIdx.x * 256 + threadIdx.x;
  if (e < E) atomicAdd(&cnt[col[e]], 1);
}
__global__ void dinv_kernel(const int* __restrict__ cnt, float* __restrict__ dinv, int n) {
  int i = blockIdx.x * 256 + threadIdx.x;
  if (i < n) dinv[i] = rsqrtf((float)cnt[i]);
}

// ---------------- two-level scan ----------------
#define SCAN_NB ((NTOT + 1023) / 1024)   // 98
__global__ __launch_bounds__(1024) void scan1_kernel(const int* __restrict__ cnt,
                                                     int* __restrict__ off,
                                                     int* __restrict__ bsum, int n) {
  __shared__ int ws[16];
  __shared__ int wexcl[16];
  const int tid = threadIdx.x, lane = tid & 63, wv = tid >> 6;
  int i = blockIdx.x * 1024 + tid;
  int v = (i < n) ? cnt[i] : 0;
  int x = v;
  #pragma unroll
  for (int o = 1; o < 64; o <<= 1) {
    int t = __shfl_up(x, o, 64);
    if (lane >= o) x += t;
  }
  if (lane == 63) ws[wv] = x;
  __syncthreads();
  if (tid < 16) {
    int y = ws[tid];
    #pragma unroll
    for (int o = 1; o < 16; o <<= 1) {
      int t = __shfl_up(y, o, 64);
      if (tid >= o) y += t;
    }
    wexcl[tid] = y - ws[tid];
    if (tid == 15) bsum[blockIdx.x] = y;
  }
  __syncthreads();
  if (i < n) off[i] = wexcl[wv] + (x - v);
}
__global__ __launch_bounds__(128) void scan2_kernel(int* __restrict__ bsum,
                                                    int* __restrict__ off, int nb, int n) {
  __shared__ int ws[2];
  const int tid = threadIdx.x, lane = tid & 63, wv = tid >> 6;
  int v = (tid < nb) ? bsum[tid] : 0;
  int x = v;
  #pragma unroll
  for (int o = 1; o < 64; o <<= 1) {
    int t = __shfl_up(x, o, 64);
    if (lane >= o) x += t;
  }
  if (lane == 63) ws[wv] = x;
  __syncthreads();
  int excl_w = (wv == 1) ? ws[0] : 0;
  if (tid < nb) bsum[tid] = excl_w + (x - v);
  if (tid == nb - 1) off[n] = excl_w + x;
}
__global__ __launch_bounds__(1024) void scan3_kernel(int* __restrict__ off,
                                                     const int* __restrict__ bsum, int n) {
  int i = blockIdx.x * 1024 + threadIdx.x;
  if (i < n) off[i] += bsum[blockIdx.x];
}

// fill CSR slots: (src, edge-norm) packed per dst segment
__global__ void fill_kernel(const int* __restrict__ row, const int* __restrict__ col,
                            const float* __restrict__ dinv, const int* __restrict__ off,
                            int* __restrict__ cur, int2* __restrict__ srcw, int E) {
  int e = blockIdx.x * 256 + threadIdx.x;
  if (e >= E) return;
  int r = row[e], c = col[e];
  float w = dinv[r] * dinv[c];
  int p = atomicAdd(&cur[c], 1);
  int2 pk; pk.x = r; pk.y = __float_as_int(w);
  srcw[off[c] + p] = pk;
}

// -------- SpMM: one wave per node, bf16 gathers, fp32 accumulate --------
// FINAL=0: write houtb (bf16 only).  FINAL=1: out = gather + X + bf16(h1).
template <int FINAL>
__global__ __launch_bounds__(256) void spmm_kernel(
    const int2* __restrict__ srcw, const int* __restrict__ off,
    const unsigned* __restrict__ hb, float* __restrict__ hout,
    unsigned* __restrict__ houtb,
    const float* __restrict__ addX, const unsigned* __restrict__ addH1) {
  int node = (int)((blockIdx.x * 256 + threadIdx.x) >> 6);
  int lane = threadIdx.x & 63;
  if (node >= NTOT) return;
  int p = off[node], pend = off[node + 1];
  float ax = 0.f, ay = 0.f;
  for (; p + 3 < pend; p += 4) {
    int2 e0 = srcw[p];
    int2 e1 = srcw[p + 1];
    int2 e2 = srcw[p + 2];
    int2 e3 = srcw[p + 3];
    unsigned u0 = hb[(size_t)e0.x * 64 + lane];
    unsigned u1 = hb[(size_t)e1.x * 64 + lane];
    unsigned u2 = hb[(size_t)e2.x * 64 + lane];
    unsigned u3 = hb[(size_t)e3.x * 64 + lane];
    float w0 = __int_as_float(e0.y), w1 = __int_as_float(e1.y);
    float w2 = __int_as_float(e2.y), w3 = __int_as_float(e3.y);
    ax += w0 * bflo(u0) + w1 * bflo(u1) + w2 * bflo(u2) + w3 * bflo(u3);
    ay += w0 * bfhi(u0) + w1 * bfhi(u1) + w2 * bfhi(u2) + w3 * bfhi(u3);
  }
  for (; p < pend; ++p) {
    int2 e0 = srcw[p];
    float w0 = __int_as_float(e0.y);
    unsigned u0 = hb[(size_t)e0.x * 64 + lane];
    ax += w0 * bflo(u0);
    ay += w0 * bfhi(u0);
  }
  if (FINAL) {
    size_t o = (size_t)node * DLAT + lane * 2;
    float2 a = *(const float2*)(addX + o);
    unsigned h1 = addH1[(size_t)node * 64 + lane];
    ax += a.x + bflo(h1);
    ay += a.y + bfhi(h1);
    float2 r; r.x = ax; r.y = ay;
    *(float2*)(hout + o) = r;
  } else {
    houtb[(size_t)node * 64 + lane] = pk2bf_fast(ax, ay);
  }
}

extern "C" void kernel_launch(void* const* d_in, const int* in_sizes, int n_in,
                              void* d_out, int out_size, void* d_ws, size_t ws_size,
                              hipStream_t stream) {
  const float* features  = (const float*)d_in[0];
  const float* preference = (const float*)d_in[1];
  const float* W1 = (const float*)d_in[2];
  const float* b1 = (const float*)d_in[3];
  const float* W2 = (const float*)d_in[4];
  const float* b2 = (const float*)d_in[5];
  const int*   edges = (const int*)d_in[6];
  const int E = in_sizes[6] / 2;
  const int* erow = edges;
  const int* ecol = edges + E;
  float* out = (float*)d_out;

  char* ws = (char*)d_ws;
  size_t off_b = 0;
  auto alloc = [&](size_t bytes) {
    void* p = ws + off_b;
    off_b = (off_b + bytes + 255) & ~(size_t)255;
    return p;
  };
  ushort*   W1T  = (ushort*)alloc((size_t)DHID * DFEAT * 2);   // 4.2 MB
  ushort*   W2T  = (ushort*)alloc((size_t)DLAT * DHID * 2);    // 0.13 MB
  ushort*   Hid  = (ushort*)alloc((size_t)MPAD * DHID * 2);    // 51.2 MB
  float*    X    = (float*)alloc((size_t)NTOT * DLAT * 4);     // 51.2 MB
  unsigned* Xb   = (unsigned*)alloc((size_t)NTOT * 64 * 4);    // 25.6 MB
  unsigned* hAb  = (unsigned*)alloc((size_t)NTOT * 64 * 4);    // 25.6 MB
  int*      cnt  = (int*)alloc((size_t)NTOT * 4);
  int*      offs = (int*)alloc((size_t)(NTOT + 1) * 4);
  int*      cur  = (int*)alloc((size_t)NTOT * 4);
  float*    dinv = (float*)alloc((size_t)NTOT * 4);
  int*      bsum = (int*)alloc((size_t)SCAN_NB * 4);
  int2*     srcw = (int2*)alloc((size_t)E * 8);                // 12.8 MB

  // projection MLP (+fused normalize for items) and user-row normalize
  prep_w1t<<<512, 256, 0, stream>>>(W1, W1T);
  prep_w2t<<<(DLAT * DHID) / 256, 256, 0, stream>>>(W2, W2T);
  gemm1_kernel<<<G1TILES, 512, 72 * 1024, stream>>>(features, W1T, b1, Hid);
  gemm2_kernel<<<MTILES, 256, 0, stream>>>(Hid, W2T, b2, X, Xb);
  normalize_pref<<<(NUSER * 64 + 255) / 256, 256, 0, stream>>>(preference, X, Xb);

  // CSR build (by destination); symmetric edge list => cnt doubles as deg
  hipMemsetAsync(cnt, 0, (size_t)NTOT * 4, stream);
  count_kernel<<<(E + 255) / 256, 256, 0, stream>>>(ecol, cnt, E);
  dinv_kernel<<<(NTOT + 255) / 256, 256, 0, stream>>>(cnt, dinv, NTOT);
  scan1_kernel<<<SCAN_NB, 1024, 0, stream>>>(cnt, offs, bsum, NTOT);
  scan2_kernel<<<1, 128, 0, stream>>>(bsum, offs, SCAN_NB, NTOT);
  scan3_kernel<<<SCAN_NB, 1024, 0, stream>>>(offs, bsum, NTOT);
  hipMemsetAsync(cur, 0, (size_t)NTOT * 4, stream);
  fill_kernel<<<(E + 255) / 256, 256, 0, stream>>>(erow, ecol, dinv, offs, cur, srcw, E);

  // two propagation layers; layer 2 fuses out = X + h1 + h2
  spmm_kernel<0><<<(NTOT * 64 + 255) / 256, 256, 0, stream>>>(srcw, offs, Xb, nullptr, hAb, nullptr, nullptr);
  spmm_kernel<1><<<(NTOT * 64 + 255) / 256, 256, 0, stream>>>(srcw, offs, hAb, out, nullptr, X, hAb);

  // output 1: preference passthrough
  hipMemcpyAsync(out + (size_t)NTOT * DLAT, preference, (size_t)NUSER * DLAT * 4,
                 hipMemcpyDeviceToDevice, stream);
}